// Round 5
// baseline (127.655 us; speedup 1.0000x reference)
//
#include <hip/hip_runtime.h>

// Problem constants (fixed by setup_inputs): B=16, T=1024, D=256, SCALE=8 -> N=128
constexpr int B = 16;
constexpr int T = 1024;
constexpr int D = 256;
constexpr int N = 128;      // T / SCALE
constexpr int D4 = D / 4;   // 64 float4 per row
constexpr float NEG_INF_V = -1e30f;

using f32x4 = float __attribute__((ext_vector_type(4)));
using f32x2 = float __attribute__((ext_vector_type(2)));

__device__ __forceinline__ f32x4 max4(f32x4 a, f32x4 b) {
    f32x4 r;
    r.x = fmaxf(a.x, b.x); r.y = fmaxf(a.y, b.y);
    r.z = fmaxf(a.z, b.z); r.w = fmaxf(a.w, b.w);
    return r;
}

// Single fused kernel. One block per (b,s), 4 waves x 64 lanes.
//  - each block computes its 16 band pooled rows DIRECTLY from feats (16x redundant
//    across blocks, but feats is 16 MB -> L2/L3-resident; hidden under store stream)
//  - zero region: wave w writes contiguous rows [w*32, w*32+32) minus band rows
//  - band rows: static prefix-max chain in registers, wave-uniform select by w
//  - meta (threads 0..127): mask2d row + bounds row (length via wave shfl-reduce)
// All stores regular/cached (nt stores measured -13% on this chip, R4).
__global__ __launch_bounds__(256) void fused_kernel(const f32x4* __restrict__ feats,
                                                    const float* __restrict__ mask,
                                                    f32x4* __restrict__ out,
                                                    f32x2* __restrict__ bounds,
                                                    float* __restrict__ m2d) {
    int blk = blockIdx.x;              // b*N + s
    int b = blk >> 7;
    int s = blk & (N - 1);
    int w = threadIdx.x >> 6;          // wave id 0..3
    int lane = threadIdx.x & 63;       // float4 index over D

    const f32x4 zero = (f32x4)0.f;
    const f32x4 ninf = (f32x4)(-INFINITY);
    f32x4* orow = out + ((size_t)blk * N) * D4 + lane;   // + e*D4

    // Phase 1: pooled rows pr[k] = max over 8 frames of (feats + (1-mask)*NEG_INF)
    // for e = s+k, plus scalar window-max of mask sk[k]. Static indices -> registers.
    const f32x4* fbase = feats + ((size_t)b * T) * D4 + lane;   // + frame*D4
    const float* mbase = mask + (size_t)b * T;
    f32x4 pr[16];
    float sk[16];
#pragma unroll
    for (int k = 0; k < 16; ++k) {
        int e = s + k;
        if (e < N) {                   // wave-uniform predicate
            f32x4 acc = ninf;
            float mm = -INFINITY;
#pragma unroll
            for (int t = 0; t < 8; ++t) {
                float m = mbase[e * 8 + t];        // wave-uniform -> broadcast
                mm = fmaxf(mm, m);
                f32x4 v = fbase[(size_t)(e * 8 + t) * D4];
                acc = max4(acc, v + (f32x4)((1.0f - m) * NEG_INF_V));
            }
            pr[k] = acc; sk[k] = mm;
        } else {
            pr[k] = ninf; sk[k] = 0.0f;
        }
    }

    // Phase 2: zero region — contiguous 32-row chunk per wave (32 KB stream).
    int band_hi = s + 15;
    int e0 = w * 32;
#pragma unroll 4
    for (int e = e0; e < e0 + 32; ++e) {
        if (e >= s && e <= band_hi) continue;            // band written below
        orow[(size_t)e * D4] = zero;
    }

    // Phase 3: static prefix-max chain, then wave-uniform select of 4 offsets.
#pragma unroll
    for (int k = 1; k < 16; ++k) pr[k] = max4(pr[k - 1], pr[k]);

    f32x4 r0, r1, r2, r3;
    float m0, m1, m2, m3;
    if (w == 0)      { r0 = pr[0]; r1 = pr[4]; r2 = pr[8];  r3 = pr[12];
                       m0 = sk[0]; m1 = sk[4]; m2 = sk[8];  m3 = sk[12]; }
    else if (w == 1) { r0 = pr[1]; r1 = pr[5]; r2 = pr[9];  r3 = pr[13];
                       m0 = sk[1]; m1 = sk[5]; m2 = sk[9];  m3 = sk[13]; }
    else if (w == 2) { r0 = pr[2]; r1 = pr[6]; r2 = pr[10]; r3 = pr[14];
                       m0 = sk[2]; m1 = sk[6]; m2 = sk[10]; m3 = sk[14]; }
    else             { r0 = pr[3]; r1 = pr[7]; r2 = pr[11]; r3 = pr[15];
                       m0 = sk[3]; m1 = sk[7]; m2 = sk[11]; m3 = sk[15]; }

#pragma unroll
    for (int t = 0; t < 4; ++t) {
        int e_t = s + w + 4 * t;
        f32x4 r = (t == 0) ? r0 : (t == 1) ? r1 : (t == 2) ? r2 : r3;
        float m = (t == 0) ? m0 : (t == 1) ? m1 : (t == 2) ? m2 : m3;
        if (e_t < N) orow[(size_t)e_t * D4] = r * (f32x4)m;
    }

    // Phase 4: meta — threads 0..127. Wave shfl-reduce of mask row for length;
    // per-thread window-max of mask for mask2d.
    if (threadIdx.x < 128) {
        int e = threadIdx.x;
        const f32x4* mr = (const f32x4*)mbase;           // 256 float4 per batch
        float sum = 0.0f;
        for (int i = lane; i < T / 4; i += 64) {
            f32x4 v = mr[i];
            sum += v.x + v.y + v.z + v.w;
        }
#pragma unroll
        for (int d = 32; d > 0; d >>= 1) sum += __shfl_xor(sum, d, 64);
        int len1 = (int)sum - 1;

        float mm = -INFINITY;
#pragma unroll
        for (int t = 0; t < 8; ++t) mm = fmaxf(mm, mbase[e * 8 + t]);
        float m = (e >= s && e <= band_hi) ? mm : 0.0f;
        m2d[(size_t)blk * N + e] = m;
        int im = (int)m;
        int b0 = min(s * 8, len1) * im;
        int b1 = min(e * 8 + 7, len1) * im;
        f32x2 bv; bv.x = (float)b0; bv.y = (float)b1;
        bounds[(size_t)blk * N + e] = bv;
    }
}

extern "C" void kernel_launch(void* const* d_in, const int* in_sizes, int n_in,
                              void* d_out, int out_size, void* d_ws, size_t ws_size,
                              hipStream_t stream) {
    const float* feats = (const float*)d_in[0];   // [B,T,D]
    const float* mask  = (const float*)d_in[1];   // [B,T]
    float* out = (float*)d_out;

    float* bounds = out + (size_t)B * N * N * D;
    float* m2d    = bounds + (size_t)B * N * N * 2;
    hipLaunchKernelGGL(fused_kernel, dim3(B * N), dim3(256), 0, stream,
                       (const f32x4*)feats, mask,
                       (f32x4*)out, (f32x2*)bounds, m2d);
}

// Round 6
// 47.655 us; speedup vs baseline: 2.6787x; 2.6787x over previous
//
#include <hip/hip_runtime.h>

// Problem constants (fixed by setup_inputs): B=16, T=1024, D=256, SCALE=8 -> N=128
constexpr int B = 16;
constexpr int T = 1024;
constexpr int D = 256;
constexpr int N = 128;      // T / SCALE
constexpr int D4 = D / 4;   // 64 float4 per row
constexpr float NEG_INF_V = -1e30f;

using f32x4 = float __attribute__((ext_vector_type(4)));
using f32x2 = float __attribute__((ext_vector_type(2)));

__device__ __forceinline__ f32x4 max4(f32x4 a, f32x4 b) {
    f32x4 r;
    r.x = fmaxf(a.x, b.x); r.y = fmaxf(a.y, b.y);
    r.z = fmaxf(a.z, b.z); r.w = fmaxf(a.w, b.w);
    return r;
}

// Kernel P: per pooled row n (one 64-lane wave each):
//   pooled[b][n][:] = max over 8 frames of (feats + (1-mask)*NEG_INF)
//   smask[b*N+n]    = window-8 max of mask (lane 0)
//   meta row s=n    : m2d[b,s,:] and bounds[b,s,:] (needs only mask -> L2-hot)
// grid: B*N/4 = 512 blocks x 256 threads.
__global__ __launch_bounds__(256) void pool_meta_kernel(const f32x4* __restrict__ feats,
                                                        const float* __restrict__ mask,
                                                        f32x4* __restrict__ pooled,
                                                        float* __restrict__ smask,
                                                        f32x2* __restrict__ bounds,
                                                        float* __restrict__ m2d) {
    int tid = threadIdx.x;
    int nloc = tid >> 6;                // 0..3
    int lane = tid & 63;                // float4 index over D
    int gidx = blockIdx.x * 4 + nloc;   // b*N + n
    int b = gidx >> 7;
    int n = gidx & (N - 1);
    const float* mbase = mask + (size_t)b * T;
    const float* mrow = mbase + (size_t)n * 8;
    const f32x4* frow = feats + ((size_t)b * T + (size_t)n * 8) * D4 + lane;
    f32x4 acc = (f32x4)(-INFINITY);
    float mmax = -INFINITY;
#pragma unroll
    for (int t = 0; t < 8; ++t) {
        float m = mrow[t];              // wave-uniform address -> broadcast
        mmax = fmaxf(mmax, m);
        float add = (1.0f - m) * NEG_INF_V;
        f32x4 v = __builtin_nontemporal_load(&frow[(size_t)t * D4]);  // read-once
        acc = max4(acc, v + (f32x4)add);
    }
    pooled[(size_t)gidx * D4 + lane] = acc;
    if (lane == 0) smask[gidx] = mmax;

    // ---- meta for row s = n ----
    // length = sum(mask[b,:]) via wave shfl-reduce (1 KB, L2-hot)
    const f32x4* mr = (const f32x4*)mbase;              // 256 float4
    float sum = 0.0f;
#pragma unroll
    for (int i = 0; i < 4; ++i) {
        f32x4 v = mr[lane + 64 * i];
        sum += v.x + v.y + v.z + v.w;
    }
#pragma unroll
    for (int d = 32; d > 0; d >>= 1) sum += __shfl_xor(sum, d, 64);
    int len1 = (int)sum - 1;

    int s = n;
#pragma unroll
    for (int h = 0; h < 2; ++h) {
        int e = lane + 64 * h;
        float mm = -INFINITY;
#pragma unroll
        for (int t = 0; t < 8; ++t) mm = fmaxf(mm, mbase[e * 8 + t]);
        float m = (e >= s && e <= s + 15) ? mm : 0.0f;
        m2d[(size_t)gidx * N + e] = m;
        int im = (int)m;
        f32x2 bv;
        bv.x = (float)(min(s * 8, len1) * im);
        bv.y = (float)(min(e * 8 + 7, len1) * im);
        bounds[(size_t)gidx * N + e] = bv;
    }
}

// Kernel F: pure feat2d fill. One block per (b,s), 4 waves x 64 lanes.
//  - all 16 band-row pooled loads issued up front (independent, in flight
//    during the zero-store stream)
//  - zero region: wave w writes contiguous rows [w*32, w*32+32) minus band rows
//  - band rows: static prefix-max chain in registers, wave-uniform select by w
// Regular cached stores (nt stores measured -13% on this chip, R4).
__global__ __launch_bounds__(256) void fill_feat2d_kernel(const f32x4* __restrict__ pooled,
                                                          const float* __restrict__ smask,
                                                          f32x4* __restrict__ out) {
    int blk = blockIdx.x;              // b*N + s
    int b = blk >> 7;
    int s = blk & (N - 1);
    int w = threadIdx.x >> 6;          // wave id 0..3
    int lane = threadIdx.x & 63;       // float4 index over D

    const f32x4 zero = (f32x4)0.f;
    const f32x4 ninf = (f32x4)(-INFINITY);
    f32x4* orow = out + ((size_t)blk * N) * D4 + lane;   // + e*D4

    // Issue all 16 band-row loads up front (static indices -> registers).
    const f32x4* prow = pooled + ((size_t)b * N) * D4 + lane;
    f32x4 pr[16];
#pragma unroll
    for (int k = 0; k < 16; ++k) {
        int e = s + k;
        pr[k] = (e < N) ? prow[(size_t)e * D4] : ninf;   // wave-uniform predicate
    }

    // Zero region: contiguous 32-row chunk per wave (32 KB sequential stream).
    int band_hi = s + 15;
    int e0 = w * 32;
#pragma unroll 4
    for (int e = e0; e < e0 + 32; ++e) {
        if (e >= s && e <= band_hi) continue;            // band written below
        orow[(size_t)e * D4] = zero;
    }

    // Static prefix-max chain: pr[k] = max(pooled[s..s+k]).
#pragma unroll
    for (int k = 1; k < 16; ++k) pr[k] = max4(pr[k - 1], pr[k]);

    // Wave w owns offsets w, w+4, w+8, w+12 (uniform branch -> static reg indices).
    f32x4 r0, r1, r2, r3;
    if (w == 0)      { r0 = pr[0]; r1 = pr[4]; r2 = pr[8];  r3 = pr[12]; }
    else if (w == 1) { r0 = pr[1]; r1 = pr[5]; r2 = pr[9];  r3 = pr[13]; }
    else if (w == 2) { r0 = pr[2]; r1 = pr[6]; r2 = pr[10]; r3 = pr[14]; }
    else             { r0 = pr[3]; r1 = pr[7]; r2 = pr[11]; r3 = pr[15]; }

    const float* sm = smask + b * N;
#pragma unroll
    for (int t = 0; t < 4; ++t) {
        int e_t = s + w + 4 * t;
        f32x4 r = (t == 0) ? r0 : (t == 1) ? r1 : (t == 2) ? r2 : r3;
        if (e_t < N) {
            float m = sm[e_t];
            orow[(size_t)e_t * D4] = r * (f32x4)m;
        }
    }
}

extern "C" void kernel_launch(void* const* d_in, const int* in_sizes, int n_in,
                              void* d_out, int out_size, void* d_ws, size_t ws_size,
                              hipStream_t stream) {
    const float* feats = (const float*)d_in[0];   // [B,T,D]
    const float* mask  = (const float*)d_in[1];   // [B,T]
    float* out = (float*)d_out;

    // workspace: pooled (B*N*D floats = 2 MB), smask (B*N floats)
    float* pooled = (float*)d_ws;
    float* smask  = pooled + (size_t)B * N * D;

    float* bounds = out + (size_t)B * N * N * D;
    float* m2d    = bounds + (size_t)B * N * N * 2;

    hipLaunchKernelGGL(pool_meta_kernel, dim3(B * N / 4), dim3(256), 0, stream,
                       (const f32x4*)feats, mask, (f32x4*)pooled, smask,
                       (f32x2*)bounds, m2d);
    hipLaunchKernelGGL(fill_feat2d_kernel, dim3(B * N), dim3(256), 0, stream,
                       (const f32x4*)pooled, smask, (f32x4*)out);
}